// Round 4
// baseline (370.244 us; speedup 1.0000x reference)
//
#include <hip/hip_runtime.h>
#include <hip/hip_bf16.h>

typedef unsigned short u16;
typedef __attribute__((ext_vector_type(4))) float f32x4;
typedef __attribute__((ext_vector_type(8))) short bf16x8;
typedef __attribute__((ext_vector_type(8))) u16 u16x8;

#define GLDS16(g, l) __builtin_amdgcn_global_load_lds( \
    (const __attribute__((address_space(1))) void*)(g), \
    (__attribute__((address_space(3))) void*)(l), 16, 0, 0)

__device__ inline u16 f2bf(float f) {
  union { float f; unsigned u; } v; v.f = f;
  unsigned r = v.u + 0x7fffu + ((v.u >> 16) & 1u);
  return (u16)(r >> 16);
}

// ---------------------------------------------------------------------------
// Kernel 1: W[o][i] = (q[o][i]-8)*scale[o][i/32] + sum_r la[o][r]*lb[r][i]
// ---------------------------------------------------------------------------
__global__ __launch_bounds__(256) void k_dequant_lora(
    const int* __restrict__ qw, const float* __restrict__ sc,
    const float* __restrict__ la, const float* __restrict__ lb,
    u16* __restrict__ W)
{
  const int I = 4096, R = 16;
  __shared__ float lbs[16][512];
  __shared__ float las[256];
  const int c0 = blockIdx.x * 512;
  const int o0 = blockIdx.y * 16;
  const int tid = threadIdx.x;

  las[tid] = la[(size_t)(o0 + (tid >> 4)) * R + (tid & 15)];
  #pragma unroll
  for (int i = 0; i < 8; ++i) {
    int idx = tid + i * 256;
    int r = idx >> 7;
    int cc4 = (idx & 127) << 2;
    *(float4*)&lbs[r][cc4] = *(const float4*)&lb[(size_t)r * I + c0 + cc4];
  }
  __syncthreads();

  const int cc = (tid & 63) * 8;
  const int rg = tid >> 6;
  #pragma unroll
  for (int rr = 0; rr < 4; ++rr) {
    const int o = o0 + rg * 4 + rr;
    float acc[8] = {0.f,0.f,0.f,0.f,0.f,0.f,0.f,0.f};
    #pragma unroll
    for (int r = 0; r < 16; ++r) {
      float av = las[(rg * 4 + rr) * 16 + r];
      float4 b0 = *(const float4*)&lbs[r][cc];
      float4 b1 = *(const float4*)&lbs[r][cc + 4];
      acc[0] += av * b0.x; acc[1] += av * b0.y;
      acc[2] += av * b0.z; acc[3] += av * b0.w;
      acc[4] += av * b1.x; acc[5] += av * b1.y;
      acc[6] += av * b1.z; acc[7] += av * b1.w;
    }
    const int4* qp = (const int4*)&qw[(size_t)o * I + c0 + cc];
    int4 q0 = qp[0], q1 = qp[1];
    float s = sc[(size_t)o * (I / 32) + ((c0 + cc) >> 5)];
    u16x8 w;
    w[0] = f2bf(((float)q0.x - 8.0f) * s + acc[0]);
    w[1] = f2bf(((float)q0.y - 8.0f) * s + acc[1]);
    w[2] = f2bf(((float)q0.z - 8.0f) * s + acc[2]);
    w[3] = f2bf(((float)q0.w - 8.0f) * s + acc[3]);
    w[4] = f2bf(((float)q1.x - 8.0f) * s + acc[4]);
    w[5] = f2bf(((float)q1.y - 8.0f) * s + acc[5]);
    w[6] = f2bf(((float)q1.z - 8.0f) * s + acc[6]);
    w[7] = f2bf(((float)q1.w - 8.0f) * s + acc[7]);
    *(u16x8*)&W[(size_t)o * I + c0 + cc] = w;
  }
}

// ---------------------------------------------------------------------------
// Kernel 2: x (f32) -> bf16
// ---------------------------------------------------------------------------
__global__ __launch_bounds__(256) void k_cvt(const float* __restrict__ x,
                                             u16* __restrict__ xb)
{
  const size_t n = (size_t)8192 * 4096;
  const size_t stride = (size_t)gridDim.x * 256 * 8;
  for (size_t i = ((size_t)blockIdx.x * 256 + threadIdx.x) * 8; i < n; i += stride) {
    float4 a = *(const float4*)&x[i];
    float4 b = *(const float4*)&x[i + 4];
    u16x8 o;
    o[0] = f2bf(a.x); o[1] = f2bf(a.y); o[2] = f2bf(a.z); o[3] = f2bf(a.w);
    o[4] = f2bf(b.x); o[5] = f2bf(b.y); o[6] = f2bf(b.z); o[7] = f2bf(b.w);
    *(u16x8*)&xb[i] = o;
  }
}

// ---------------------------------------------------------------------------
// Kernel 3: C[M,N] = A[M,K] @ B[N,K]^T + bias
// 256x256 tile, BK=32, 4-deep LDS ring, 8 waves (2Mx4N), 512 threads.
// Round-4 change: m201 8-phase dual-barrier schedule. Per K-tile, 2 phases:
//   { ds_read frags ; stage prefetch ; bar ; lgkmcnt(0) ; setprio(1) ;
//     16 MFMA ; setprio(0) ; bar }
// Counted vmcnt(4) once per K-tile (phase B, before its first barrier) ->
// loads stay in flight across barriers. The dual-barrier phases create wave
// role diversity so LDS pipe (reads) and matrix pipe interleave instead of
// convoying (round-3 profile: MfmaUtil 50% = exact no-overlap ratio).
// ---------------------------------------------------------------------------
__global__ __launch_bounds__(512, 1) void k_gemm(
    const u16* __restrict__ A, const u16* __restrict__ B,
    const float* __restrict__ bias, float* __restrict__ C)
{
  const int N = 4096, K = 4096;
  const int NTK = 128;                 // K / 32
  __shared__ u16 As[4 * 8192];         // 4 ring buffers x [256 rows][32 k]
  __shared__ u16 Bs[4 * 8192];

  // XCD swizzle: 512 blocks = 8 XCDs x 64
  const int bid = blockIdx.x;
  const int swz = (bid & 7) * 64 + (bid >> 3);
  const int m0 = (swz >> 4) * 256;     // 32 M-tiles
  const int n0 = (swz & 15) * 256;     // 16 N-tiles

  const int tid = threadIdx.x;
  const int wid = tid >> 6, lane = tid & 63;
  const int wid_m = wid >> 2, wid_n = wid & 3;

  // staging geometry (refcheck-passed rounds 1-3)
  const int st0 = wid;
  const int st1 = 8 + wid;
  const int srow = lane >> 2;
  const int schunk = (((lane & 3) ^ (((lane >> 5) & 1) << 1))) * 8;
  const u16* Asrc0 = A + (size_t)(m0 + st0 * 16 + srow) * K + schunk;
  const u16* Asrc1 = A + (size_t)(m0 + st1 * 16 + srow) * K + schunk;
  const u16* Bsrc0 = B + (size_t)(n0 + st0 * 16 + srow) * K + schunk;
  const u16* Bsrc1 = B + (size_t)(n0 + st1 * 16 + srow) * K + schunk;

#define STAGE_A(buf, t) do { \
    GLDS16(Asrc0 + (size_t)(t) * 32, &As[(buf) * 8192 + st0 * 512]); \
    GLDS16(Asrc1 + (size_t)(t) * 32, &As[(buf) * 8192 + st1 * 512]); } while (0)
#define STAGE_B(buf, t) do { \
    GLDS16(Bsrc0 + (size_t)(t) * 32, &Bs[(buf) * 8192 + st0 * 512]); \
    GLDS16(Bsrc1 + (size_t)(t) * 32, &Bs[(buf) * 8192 + st1 * 512]); } while (0)

  // swizzled fragment read offset (measured 0 bank conflicts)
  const int LA = (lane & 15) * 32 + (((lane >> 4) * 8) ^ ((lane & 8) ? 16 : 0));
  const int wmb = wid_m * 8;           // A frag base (8 m-frags per wave)
  const int wnb = wid_n * 4;           // B frag base (4 n-frags per wave)

  f32x4 acc[8][4] = {};
  bf16x8 af[4], bf[4];

  // ---- prologue: stage tiles 0,1; wait tile 0 ----
  STAGE_A(0, 0); STAGE_B(0, 0);
  STAGE_A(1, 1); STAGE_B(1, 1);
  asm volatile("s_waitcnt vmcnt(4)" ::: "memory");   // tile 0 landed
  __builtin_amdgcn_s_barrier();

  for (int t = 0; t < NTK; ++t) {
    const int b_ = t & 3;

    // ======== phase A: read a(m0-3)+b(n0-3), stage A(t+2), MFMA m0-3 ========
    #pragma unroll
    for (int m = 0; m < 4; ++m)
      af[m] = *(const bf16x8*)&As[b_ * 8192 + (wmb + m) * 512 + LA];
    #pragma unroll
    for (int n = 0; n < 4; ++n)
      bf[n] = *(const bf16x8*)&Bs[b_ * 8192 + (wnb + n) * 512 + LA];
    if (t + 2 < NTK) STAGE_A((t + 2) & 3, t + 2);
    __builtin_amdgcn_sched_barrier(0);
    __builtin_amdgcn_s_barrier();
    asm volatile("s_waitcnt lgkmcnt(0)" ::: "memory");
    __builtin_amdgcn_sched_barrier(0);
    __builtin_amdgcn_s_setprio(1);
    #pragma unroll
    for (int m = 0; m < 4; ++m)
      #pragma unroll
      for (int n = 0; n < 4; ++n)
        acc[m][n] = __builtin_amdgcn_mfma_f32_16x16x32_bf16(af[m], bf[n], acc[m][n], 0, 0, 0);
    __builtin_amdgcn_s_setprio(0);
    __builtin_amdgcn_sched_barrier(0);
    __builtin_amdgcn_s_barrier();

    // ======== phase B: read a(m4-7), stage B(t+2), vmcnt(4), MFMA m4-7 ======
    #pragma unroll
    for (int m = 0; m < 4; ++m)
      af[m] = *(const bf16x8*)&As[b_ * 8192 + (wmb + 4 + m) * 512 + LA];
    if (t + 2 < NTK) {
      STAGE_B((t + 2) & 3, t + 2);
      asm volatile("s_waitcnt vmcnt(4)" ::: "memory");  // tile t+1 landed
    } else {
      asm volatile("s_waitcnt vmcnt(0)" ::: "memory");
    }
    __builtin_amdgcn_sched_barrier(0);
    __builtin_amdgcn_s_barrier();
    asm volatile("s_waitcnt lgkmcnt(0)" ::: "memory");
    __builtin_amdgcn_sched_barrier(0);
    __builtin_amdgcn_s_setprio(1);
    #pragma unroll
    for (int m = 0; m < 4; ++m)
      #pragma unroll
      for (int n = 0; n < 4; ++n)
        acc[4 + m][n] = __builtin_amdgcn_mfma_f32_16x16x32_bf16(af[m], bf[n], acc[4 + m][n], 0, 0, 0);
    __builtin_amdgcn_s_setprio(0);
    __builtin_amdgcn_sched_barrier(0);
    __builtin_amdgcn_s_barrier();
  }
#undef STAGE_A
#undef STAGE_B

  // ---- epilogue: C/D layout col=lane&15, row=(lane>>4)*4+j ----
  const int crow = m0 + wid_m * 128 + ((lane >> 4) << 2);
  const int ccol = n0 + wid_n * 64 + (lane & 15);
  #pragma unroll
  for (int n = 0; n < 4; ++n) {
    float bv = bias[ccol + n * 16];
    #pragma unroll
    for (int m = 0; m < 8; ++m) {
      #pragma unroll
      for (int j = 0; j < 4; ++j) {
        C[(size_t)(crow + m * 16 + j) * N + ccol + n * 16] = acc[m][n][j] + bv;
      }
    }
  }
}

// ---------------------------------------------------------------------------
extern "C" void kernel_launch(void* const* d_in, const int* in_sizes, int n_in,
                              void* d_out, int out_size, void* d_ws, size_t ws_size,
                              hipStream_t stream) {
  const float* x    = (const float*)d_in[0];   // [8192, 4096] f32
  const int*   qw   = (const int*)d_in[1];     // [4096, 4096] i32
  const float* sc   = (const float*)d_in[2];   // [4096, 128]  f32
  const float* la   = (const float*)d_in[3];   // [4096, 16]   f32
  const float* lb   = (const float*)d_in[4];   // [16, 4096]   f32
  const float* bias = (const float*)d_in[5];   // [4096]       f32
  float* y = (float*)d_out;                    // [8192, 4096] f32

  u16* W  = (u16*)d_ws;                                        // 32 MiB
  u16* Xb = (u16*)((char*)d_ws + (size_t)32 * 1024 * 1024);    // 64 MiB

  dim3 gridD(4096 / 512, 4096 / 16);
  k_dequant_lora<<<gridD, 256, 0, stream>>>(qw, sc, la, lb, W);
  k_cvt<<<2048, 256, 0, stream>>>(x, Xb);
  const int ngemm = (8192 / 256) * (4096 / 256);   // 512
  k_gemm<<<ngemm, 512, 0, stream>>>(Xb, W, bias, y);
}